// Round 1
// baseline (1969.447 us; speedup 1.0000x reference)
//
#include <hip/hip_runtime.h>
#include <math.h>

constexpr int Bc = 2, Nseq = 1024, Dh = 512, Nh = 16, Dhead = 32, Dff = 2048;
constexpr float FACT = 0.08838834764831845f; // 0.5/sqrt(32)

// ---------------- LayerNorm (one block per row, 512 cols) ----------------
__global__ __launch_bounds__(256) void ln_kernel(const float* __restrict__ x,
                                                 const float* __restrict__ g,
                                                 const float* __restrict__ b,
                                                 float* __restrict__ y) {
    int row = blockIdx.x;
    const float* xr = x + (long)row * Dh;
    float* yr = y + (long)row * Dh;
    int tid = threadIdx.x;
    float v0 = xr[tid], v1 = xr[tid + 256];
    __shared__ float red[256];
    red[tid] = v0 + v1;
    __syncthreads();
    for (int o = 128; o > 0; o >>= 1) { if (tid < o) red[tid] += red[tid + o]; __syncthreads(); }
    float mean = red[0] * (1.0f / Dh);
    __syncthreads();
    float d0 = v0 - mean, d1 = v1 - mean;
    red[tid] = d0 * d0 + d1 * d1;
    __syncthreads();
    for (int o = 128; o > 0; o >>= 1) { if (tid < o) red[tid] += red[tid + o]; __syncthreads(); }
    float rstd = rsqrtf(red[0] * (1.0f / Dh) + 1e-5f);
    yr[tid]       = d0 * rstd * g[tid] + b[tid];
    yr[tid + 256] = d1 * rstd * g[tid + 256] + b[tid + 256];
}

// ---------------- Generic tiled f32 GEMM: C = A@W (+bias) (+resid) (+silu) ----------------
// BM=BN=64, BK=16, 256 threads, 4x4 per thread. M%64==0, Nn%64==0, K%16==0.
__global__ __launch_bounds__(256) void gemm_f32(
    const float* __restrict__ A, int lda, long sAz,
    const float* __restrict__ W, int ldw, long sWz,
    float* __restrict__ C, int ldc, long sCz,
    const float* __restrict__ bias,
    const float* __restrict__ resid, int ldr,
    int M, int Nn, int K, int act)
{
    A += (long)blockIdx.z * sAz;
    W += (long)blockIdx.z * sWz;
    C += (long)blockIdx.z * sCz;
    __shared__ float As[16][64];
    __shared__ float Bs[16][64];
    int tid = threadIdx.x;
    int tx = tid & 15, ty = tid >> 4;
    int m0 = blockIdx.y * 64, n0 = blockIdx.x * 64;
    float acc[4][4] = {};
    for (int k0 = 0; k0 < K; k0 += 16) {
#pragma unroll
        for (int r = 0; r < 4; r++) {
            int t = tid + r * 256;
            int mm = t >> 4, kk = t & 15;
            As[kk][mm] = A[(long)(m0 + mm) * lda + k0 + kk];
        }
#pragma unroll
        for (int r = 0; r < 4; r++) {
            int t = tid + r * 256;
            int kk = t >> 6, nn = t & 63;
            Bs[kk][nn] = W[(long)(k0 + kk) * ldw + n0 + nn];
        }
        __syncthreads();
#pragma unroll
        for (int kk = 0; kk < 16; kk++) {
            float a[4], bb[4];
#pragma unroll
            for (int i = 0; i < 4; i++) a[i] = As[kk][ty * 4 + i];
#pragma unroll
            for (int j = 0; j < 4; j++) bb[j] = Bs[kk][tx * 4 + j];
#pragma unroll
            for (int i = 0; i < 4; i++)
#pragma unroll
                for (int j = 0; j < 4; j++) acc[i][j] += a[i] * bb[j];
        }
        __syncthreads();
    }
#pragma unroll
    for (int i = 0; i < 4; i++) {
        int m = m0 + ty * 4 + i;
#pragma unroll
        for (int j = 0; j < 4; j++) {
            int n = n0 + tx * 4 + j;
            float c = acc[i][j];
            if (bias) c += bias[n];
            if (resid) c += resid[(long)m * ldr + n];
            if (act == 1) c = c / (1.0f + __expf(-c)); // silu
            C[(long)m * ldc + n] = c;
        }
    }
}

// ---------------- scores = FACT*Hq@Hk^T + rbf + D (masked), per-(b,h) slice ----------------
__global__ __launch_bounds__(256) void score_kernel(
    const float* __restrict__ Hq, const float* __restrict__ Hk,
    const float* __restrict__ rbf, const float* __restrict__ Dm,
    const int* __restrict__ mask, float* __restrict__ scores, int slice0)
{
    int slice = slice0 + blockIdx.z;
    int b = slice >> 4, h = slice & 15;
    const int lda = Nh * 4 * Dhead; // 2048
    const float* q = Hq + (long)b * Nseq * lda + h * (4 * Dhead);
    const float* k = Hk + (long)b * Nseq * lda + h * (4 * Dhead);
    const float* rb = rbf + (long)slice * Nseq * Nseq;
    const float* Dp = Dm + (long)b * Nseq * Nseq;
    const int* mp = mask + b * Nseq;
    float* out = scores + (long)blockIdx.z * Nseq * Nseq;

    __shared__ float As[16][64]; // [k][n]
    __shared__ float Bs[16][64]; // [k][m]
    int tid = threadIdx.x;
    int tx = tid & 15, ty = tid >> 4;
    int n0 = blockIdx.y * 64, m0 = blockIdx.x * 64;
    float acc[4][4] = {};
    for (int k0 = 0; k0 < 4 * Dhead; k0 += 16) {
#pragma unroll
        for (int r = 0; r < 4; r++) {
            int t = tid + r * 256;
            int rr = t >> 4, kk = t & 15;
            As[kk][rr] = q[(long)(n0 + rr) * lda + k0 + kk];
            Bs[kk][rr] = k[(long)(m0 + rr) * lda + k0 + kk];
        }
        __syncthreads();
#pragma unroll
        for (int kk = 0; kk < 16; kk++) {
            float a[4], bb[4];
#pragma unroll
            for (int i = 0; i < 4; i++) a[i] = As[kk][ty * 4 + i];
#pragma unroll
            for (int j = 0; j < 4; j++) bb[j] = Bs[kk][tx * 4 + j];
#pragma unroll
            for (int i = 0; i < 4; i++)
#pragma unroll
                for (int j = 0; j < 4; j++) acc[i][j] += a[i] * bb[j];
        }
        __syncthreads();
    }
#pragma unroll
    for (int i = 0; i < 4; i++) {
        int n = n0 + ty * 4 + i;
#pragma unroll
        for (int j = 0; j < 4; j++) {
            int m = m0 + tx * 4 + j;
            float s = acc[i][j] * FACT + rb[(long)n * Nseq + m] + Dp[(long)n * Nseq + m];
            if (mp[m] == 0) s = -1e30f;
            out[(long)n * Nseq + m] = s;
        }
    }
}

// ---------------- row softmax, in place, rows of 1024 ----------------
__global__ __launch_bounds__(256) void softmax_kernel(float* __restrict__ scores) {
    float* p = scores + (long)blockIdx.y * Nseq * Nseq + (long)blockIdx.x * Nseq;
    int tid = threadIdx.x;
    float v[4];
    float mx = -INFINITY;
#pragma unroll
    for (int r = 0; r < 4; r++) { v[r] = p[tid + r * 256]; mx = fmaxf(mx, v[r]); }
    __shared__ float red[256];
    red[tid] = mx;
    __syncthreads();
    for (int o = 128; o > 0; o >>= 1) { if (tid < o) red[tid] = fmaxf(red[tid], red[tid + o]); __syncthreads(); }
    mx = red[0];
    __syncthreads();
    float s = 0.f;
#pragma unroll
    for (int r = 0; r < 4; r++) { v[r] = __expf(v[r] - mx); s += v[r]; }
    red[tid] = s;
    __syncthreads();
    for (int o = 128; o > 0; o >>= 1) { if (tid < o) red[tid] += red[tid + o]; __syncthreads(); }
    float inv = 1.0f / red[0];
#pragma unroll
    for (int r = 0; r < 4; r++) p[tid + r * 256] = v[r] * inv;
}

// ---------------- gather V_attn[b,m,h,0:128] = concat(Hv, Vv) ----------------
__global__ __launch_bounds__(256) void vattn_gather(const float* __restrict__ Hv,
                                                    const float* __restrict__ VvR,
                                                    float* __restrict__ Vattn) {
    int idx = blockIdx.x * 256 + threadIdx.x; // B*N*NH*128
    int d = idx & 127;
    int h = (idx >> 7) & 15;
    int bm = idx >> 11;
    float val;
    if (d < Dhead) {
        val = Hv[(long)bm * Dh + h * Dhead + d];
    } else {
        int c = (d - Dhead) >> 5, dd = (d - Dhead) & 31;
        val = VvR[((long)bm * 3 + c) * Dh + h * Dhead + dd];
    }
    Vattn[idx] = val;
}

// ---------------- split res into H_res (B,N,512) and V_res (B,N,3,512) ----------------
__global__ __launch_bounds__(256) void res_split(const float* __restrict__ res,
                                                 float* __restrict__ Hres,
                                                 float* __restrict__ Vres) {
    int idx = blockIdx.x * 256 + threadIdx.x; // B*N*NH*128
    int d = idx & 127;
    int h = (idx >> 7) & 15;
    int bm = idx >> 11;
    float val = res[idx];
    if (d < Dhead) {
        Hres[(long)bm * Dh + h * Dhead + d] = val;
    } else {
        int c = (d - Dhead) >> 5, dd = (d - Dhead) & 31;
        Vres[((long)bm * 3 + c) * Dh + h * Dhead + dd] = val;
    }
}

// ---------------- scaler = concat(Hn2, ||V1||_over_c) ----------------
__global__ __launch_bounds__(256) void scaler_kernel(const float* __restrict__ Hn2,
                                                     const float* __restrict__ Vp,
                                                     float* __restrict__ scaler) {
    int idx = blockIdx.x * 256 + threadIdx.x; // B*N*512
    int j = idx & 511;
    int row = idx >> 9;
    scaler[(long)row * 1024 + j] = Hn2[idx];
    float ss = 0.f;
#pragma unroll
    for (int c = 0; c < 3; c++) {
        float v = Vp[((long)row * 3 + c) * 1024 + j];
        ss += v * v;
    }
    scaler[(long)row * 1024 + 512 + j] = sqrtf(ss);
}

// ---------------- final: H += s[:512]; V += s[512:] * V2 ----------------
__global__ __launch_bounds__(256) void final_kernel(float* __restrict__ outH,
                                                    float* __restrict__ outV,
                                                    const float* __restrict__ s,
                                                    const float* __restrict__ Vp) {
    int idx = blockIdx.x * 256 + threadIdx.x; // B*N*512
    int j = idx & 511;
    int row = idx >> 9;
    outH[idx] += s[(long)row * 1024 + j];
    float vu = s[(long)row * 1024 + 512 + j];
#pragma unroll
    for (int c = 0; c < 3; c++) {
        long vi = ((long)row * 3 + c) * Dh + j;
        outV[vi] += vu * Vp[((long)row * 3 + c) * 1024 + 512 + j];
    }
}

extern "C" void kernel_launch(void* const* d_in, const int* in_sizes, int n_in,
                              void* d_out, int out_size, void* d_ws, size_t ws_size,
                              hipStream_t stream) {
    const float* H    = (const float*)d_in[0];
    const float* V    = (const float*)d_in[1];
    const float* Dm   = (const float*)d_in[2];
    const float* rbf  = (const float*)d_in[3];
    const int*   mask = (const int*)d_in[4];
    const float* Wq   = (const float*)d_in[5];
    const float* bq   = (const float*)d_in[6];
    const float* Wk   = (const float*)d_in[7];
    const float* bk   = (const float*)d_in[8];
    const float* Wvs  = (const float*)d_in[9];
    const float* bvs  = (const float*)d_in[10];
    const float* Wvv  = (const float*)d_in[11];
    const float* Wo   = (const float*)d_in[12];
    const float* bo   = (const float*)d_in[13];
    const float* Wvo  = (const float*)d_in[14];
    const float* ln1g = (const float*)d_in[15];
    const float* ln1b = (const float*)d_in[16];
    const float* Wlv  = (const float*)d_in[17];
    const float* W1   = (const float*)d_in[18];
    const float* b1   = (const float*)d_in[19];
    const float* W2   = (const float*)d_in[20];
    const float* b2   = (const float*)d_in[21];
    const float* ln2g = (const float*)d_in[22];
    const float* ln2b = (const float*)d_in[23];

    char* ws = (char*)d_ws;
    auto F = [&](size_t mb) { return (float*)(ws + mb * 1024ul * 1024ul); };
    // phase-1 arena
    float* Hn    = F(0);   // 4MB
    float* HqB   = F(4);   // 16MB
    float* HkB   = F(20);  // 16MB
    float* HvB   = F(36);  // 4MB
    float* VvR   = F(40);  // 12MB
    float* Vattn = F(52);  // 16MB
    float* resb  = F(68);  // 16MB
    float* scb   = F(84);  // 16MB (4 slices)
    // phase-2 arena (reuses dead phase-1 space)
    float* Hres   = F(0);   // 4MB
    float* Vres   = F(4);   // 12MB
    float* Hn2    = F(16);  // 4MB
    float* Vp     = F(20);  // 24MB
    float* scaler = F(44);  // 8MB
    float* t1     = F(52);  // 16MB
    float* sbuf   = F(68);  // 8MB

    float* outH = (float*)d_out;
    float* outV = outH + (size_t)Bc * Nseq * Dh;

    const int rows = Bc * Nseq;       // 2048
    const int vrows = Bc * Nseq * 3;  // 6144

    // 1. LN1
    ln_kernel<<<rows, 256, 0, stream>>>(H, ln1g, ln1b, Hn);
    // 2. Hq, Hk, Hv, VvRaw
    gemm_f32<<<dim3(32, 32, 1), 256, 0, stream>>>(Hn, 512, 0, Wq, 2048, 0, HqB, 2048, 0,
                                                  bq, nullptr, 0, rows, 2048, 512, 0);
    gemm_f32<<<dim3(32, 32, 1), 256, 0, stream>>>(Hn, 512, 0, Wk, 2048, 0, HkB, 2048, 0,
                                                  bk, nullptr, 0, rows, 2048, 512, 0);
    gemm_f32<<<dim3(8, 32, 1), 256, 0, stream>>>(Hn, 512, 0, Wvs, 512, 0, HvB, 512, 0,
                                                 bvs, nullptr, 0, rows, 512, 512, 0);
    gemm_f32<<<dim3(8, 96, 1), 256, 0, stream>>>(V, 512, 0, Wvv, 512, 0, VvR, 512, 0,
                                                 nullptr, nullptr, 0, vrows, 512, 512, 0);
    // 3. V_attn gather
    vattn_gather<<<16384, 256, 0, stream>>>(HvB, VvR, Vattn);
    // 4. attention: 8 rounds of 4 (b,h) slices
    for (int r = 0; r < 8; r++) {
        int slice0 = r * 4;
        int b = slice0 >> 4, h0 = slice0 & 15;
        score_kernel<<<dim3(16, 16, 4), 256, 0, stream>>>(HqB, HkB, rbf, Dm, mask, scb, slice0);
        softmax_kernel<<<dim3(1024, 4), 256, 0, stream>>>(scb);
        gemm_f32<<<dim3(2, 16, 4), 256, 0, stream>>>(
            scb, 1024, (long)Nseq * Nseq,
            Vattn + (size_t)b * Nseq * 2048 + (size_t)h0 * 128, 2048, 128,
            resb + (size_t)b * Nseq * 2048 + (size_t)h0 * 128, 2048, 128,
            nullptr, nullptr, 0, Nseq, 128, Nseq, 0);
    }
    // 5. split res
    res_split<<<16384, 256, 0, stream>>>(resb, Hres, Vres);
    // 6. H_new = H + Hres@Wo + bo  (into d_out)
    gemm_f32<<<dim3(8, 32, 1), 256, 0, stream>>>(Hres, 512, 0, Wo, 512, 0, outH, 512, 0,
                                                 bo, H, 512, rows, 512, 512, 0);
    // 7. V_new = V + Vres@Wvo      (into d_out)
    gemm_f32<<<dim3(8, 96, 1), 256, 0, stream>>>(Vres, 512, 0, Wvo, 512, 0, outV, 512, 0,
                                                 nullptr, V, 512, vrows, 512, 512, 0);
    // 8. LN2 on H_new
    ln_kernel<<<rows, 256, 0, stream>>>(outH, ln2g, ln2b, Hn2);
    // 9. Vp = V_new @ Wlv (B,N,3,1024)
    gemm_f32<<<dim3(16, 96, 1), 256, 0, stream>>>(outV, 512, 0, Wlv, 1024, 0, Vp, 1024, 0,
                                                  nullptr, nullptr, 0, vrows, 1024, 512, 0);
    // 10. scaler = [Hn2, ||V1||]
    scaler_kernel<<<4096, 256, 0, stream>>>(Hn2, Vp, scaler);
    // 11. t1 = silu(scaler@W1 + b1)
    gemm_f32<<<dim3(32, 32, 1), 256, 0, stream>>>(scaler, 1024, 0, W1, 2048, 0, t1, 2048, 0,
                                                  b1, nullptr, 0, rows, 2048, 1024, 1);
    // 12. s = t1@W2 + b2
    gemm_f32<<<dim3(16, 32, 1), 256, 0, stream>>>(t1, 2048, 0, W2, 1024, 0, sbuf, 1024, 0,
                                                  b2, nullptr, 0, rows, 1024, 2048, 0);
    // 13. final in-place update of d_out
    final_kernel<<<4096, 256, 0, stream>>>(outH, outV, sbuf, Vp);
}

// Round 3
// 789.479 us; speedup vs baseline: 2.4946x; 2.4946x over previous
//
#include <hip/hip_runtime.h>
#include <math.h>

constexpr int Bc = 2, Nseq = 1024, Dh = 512, Nh = 16, Dhead = 32;
constexpr float FACT = 0.08838834764831845f; // 0.5/sqrt(32)

typedef __attribute__((ext_vector_type(8))) __bf16 bf16x8;
typedef __attribute__((ext_vector_type(4))) float f32x4;

__device__ __forceinline__ short f2b(float x) {
    union { float f; unsigned u; } v; v.f = x;
    unsigned r = v.u + 0x7fffu + ((v.u >> 16) & 1u);
    return (short)(r >> 16);
}

// ---- shared 128x128-tile bf16 MFMA mainloop (A[M][K], B[N][K], both row-major bf16) ----
// Register-staged LDS (global load -> ds_write_b128), XOR chunk swizzle on the
// LDS write side, matching XOR on the read side. Fully compiler-ordered.
__device__ __forceinline__ void mfma_loop(const short* __restrict__ A, int lda,
                                          const short* __restrict__ B, int ldb,
                                          int K, short* __restrict__ smA,
                                          short* __restrict__ smB, f32x4 acc[4][4]) {
    const int tid = threadIdx.x;
    const int lane = tid & 63;
    const int w = tid >> 6;
    const int wr = (w >> 1) * 64, wc = (w & 1) * 64;
    const int lr = lane & 15;
    const int srow = tid >> 3;  // 0..31
    const int scol = tid & 7;   // 16B chunk 0..7
    for (int k0 = 0; k0 < K; k0 += 64) {
        bf16x8 ta[4], tb[4];
#pragma unroll
        for (int r = 0; r < 4; r++) {
            int row = r * 32 + srow;
            ta[r] = *(const bf16x8*)(A + (long)row * lda + k0 + scol * 8);
            tb[r] = *(const bf16x8*)(B + (long)row * ldb + k0 + scol * 8);
        }
        __syncthreads();  // prior iteration's LDS reads complete
#pragma unroll
        for (int r = 0; r < 4; r++) {
            int row = r * 32 + srow;
            int c = scol ^ (row & 7);
            *(bf16x8*)(smA + row * 64 + c * 8) = ta[r];
            *(bf16x8*)(smB + row * 64 + c * 8) = tb[r];
        }
        __syncthreads();  // LDS writes visible
#pragma unroll
        for (int h = 0; h < 2; h++) {
            int cb = h * 4 + (lane >> 4);
            bf16x8 af[4], bv[4];
#pragma unroll
            for (int i = 0; i < 4; i++) {
                int row = wr + i * 16 + lr;
                af[i] = *(const bf16x8*)(smA + row * 64 + ((cb ^ (row & 7)) << 3));
            }
#pragma unroll
            for (int j = 0; j < 4; j++) {
                int row = wc + j * 16 + lr;
                bv[j] = *(const bf16x8*)(smB + row * 64 + ((cb ^ (row & 7)) << 3));
            }
#pragma unroll
            for (int i = 0; i < 4; i++)
#pragma unroll
                for (int j = 0; j < 4; j++)
                    acc[i][j] = __builtin_amdgcn_mfma_f32_16x16x32_bf16(af[i], bv[j], acc[i][j], 0, 0, 0);
        }
    }
}

// ---- generic GEMM: C = A @ B^T (+bias)(+resid)(silu), out f32 or bf16 ----
// flags: 1 = silu, 2 = output bf16
__global__ __launch_bounds__(256) void gemm_bf16(
    const short* __restrict__ A, int lda, long sAz,
    const short* __restrict__ B, int ldb, long sBz,
    void* __restrict__ C, int ldc, long sCz,
    const float* __restrict__ bias,
    const float* __restrict__ resid, int ldr, long sRz,
    int K, int flags)
{
    __shared__ short smA[128 * 64], smB[128 * 64];
    const long z = blockIdx.z;
    const short* Ab = A + z * sAz + (long)blockIdx.y * 128 * lda;
    const short* Bb = B + z * sBz + (long)blockIdx.x * 128 * ldb;
    f32x4 acc[4][4] = {};
    mfma_loop(Ab, lda, Bb, ldb, K, smA, smB, acc);
    const int tid = threadIdx.x, lane = tid & 63, w = tid >> 6;
    const int wr = (w >> 1) * 64, wc = (w & 1) * 64, lr = lane & 15, r0 = (lane >> 4) * 4;
    const int m0 = blockIdx.y * 128, n0 = blockIdx.x * 128;
    float* Cf = (float*)C; short* Cs = (short*)C;
    const float* rz = resid ? resid + z * sRz : nullptr;
#pragma unroll
    for (int i = 0; i < 4; i++)
#pragma unroll
        for (int j = 0; j < 4; j++) {
            int col = n0 + wc + j * 16 + lr;
            float bv = bias ? bias[col] : 0.f;
#pragma unroll
            for (int q = 0; q < 4; q++) {
                int row = m0 + wr + i * 16 + r0 + q;
                float c = acc[i][j][q] + bv;
                if (rz) c += rz[(long)row * ldr + col];
                if (flags & 1) c = c / (1.f + __expf(-c));
                long off = z * sCz + (long)row * ldc + col;
                if (flags & 2) Cs[off] = f2b(c); else Cf[off] = c;
            }
        }
}

// ---- scores = FACT*q@k^T + rbf + D (masked) -> f32, per-slice ----
__global__ __launch_bounds__(256) void score_mfma(
    const short* __restrict__ Hq, const short* __restrict__ Hk,
    const float* __restrict__ rbf, const float* __restrict__ Dm,
    const int* __restrict__ mask, float* __restrict__ scb, int slice0)
{
    __shared__ short smA[128 * 64], smB[128 * 64];
    int slice = slice0 + blockIdx.z;
    int b = slice >> 4, h = slice & 15;
    const short* q = Hq + (long)b * Nseq * 2048 + h * 128 + (long)blockIdx.y * 128 * 2048;
    const short* k = Hk + (long)b * Nseq * 2048 + h * 128 + (long)blockIdx.x * 128 * 2048;
    f32x4 acc[4][4] = {};
    mfma_loop(q, 2048, k, 2048, 128, smA, smB, acc);
    const float* rb = rbf + (long)slice * Nseq * Nseq;
    const float* Dp = Dm + (long)b * Nseq * Nseq;
    const int* mp = mask + b * Nseq;
    float* out = scb + (long)blockIdx.z * Nseq * Nseq;
    const int tid = threadIdx.x, lane = tid & 63, w = tid >> 6;
    const int wr = (w >> 1) * 64, wc = (w & 1) * 64, lr = lane & 15, r0 = (lane >> 4) * 4;
    const int n0 = blockIdx.y * 128, m0 = blockIdx.x * 128;
#pragma unroll
    for (int i = 0; i < 4; i++)
#pragma unroll
        for (int j = 0; j < 4; j++) {
            int m = m0 + wc + j * 16 + lr;
            bool live = (mp[m] != 0);
#pragma unroll
            for (int q4 = 0; q4 < 4; q4++) {
                int n = n0 + wr + i * 16 + r0 + q4;
                float s = acc[i][j][q4] * FACT + rb[(long)n * Nseq + m] + Dp[(long)n * Nseq + m];
                out[(long)n * Nseq + m] = live ? s : -1e30f;
            }
        }
}

// ---- res = P @ Vattn_t^T, scattered directly into bf16 Hres / Vres ----
__global__ __launch_bounds__(256) void pv_mfma(
    const short* __restrict__ P, const short* __restrict__ VaT,
    short* __restrict__ Hres, short* __restrict__ Vres, int slice0)
{
    __shared__ short smA[128 * 64], smB[128 * 64];
    int slice = slice0 + blockIdx.z;
    int b = slice >> 4, h = slice & 15;
    const short* Ab = P + (long)blockIdx.z * Nseq * 1024 + (long)blockIdx.y * 128 * 1024;
    const short* Bb = VaT + (long)slice * 128 * Nseq;
    f32x4 acc[4][4] = {};
    mfma_loop(Ab, 1024, Bb, 1024, 1024, smA, smB, acc);
    const int tid = threadIdx.x, lane = tid & 63, w = tid >> 6;
    const int wr = (w >> 1) * 64, wc = (w & 1) * 64, lr = lane & 15, r0 = (lane >> 4) * 4;
#pragma unroll
    for (int i = 0; i < 4; i++)
#pragma unroll
        for (int j = 0; j < 4; j++) {
            int d = wc + j * 16 + lr;
#pragma unroll
            for (int q4 = 0; q4 < 4; q4++) {
                int n = blockIdx.y * 128 + wr + i * 16 + r0 + q4;
                float c = acc[i][j][q4];
                if (d < 32) Hres[((long)b * Nseq + n) * 512 + h * 32 + d] = f2b(c);
                else {
                    int c3 = (d - 32) >> 5, dd = (d - 32) & 31;
                    Vres[(((long)b * Nseq + n) * 3 + c3) * 512 + h * 32 + dd] = f2b(c);
                }
            }
        }
}

// ---- weight transpose + f32->bf16: Wt[n][k] = W[k][n] ----
__global__ __launch_bounds__(256) void tconv(const float* __restrict__ W,
                                             short* __restrict__ Wt, int K, int N) {
    __shared__ float t[32][33];
    int n0 = blockIdx.x * 32, k0 = blockIdx.y * 32;
    int tx = threadIdx.x & 31, ty = threadIdx.x >> 5;
#pragma unroll
    for (int r = 0; r < 4; r++) t[ty + r * 8][tx] = W[(long)(k0 + ty + r * 8) * N + n0 + tx];
    __syncthreads();
#pragma unroll
    for (int r = 0; r < 4; r++) Wt[(long)(n0 + ty + r * 8) * K + k0 + tx] = f2b(t[tx][ty + r * 8]);
}

// ---- f32 -> bf16 convert, 4/thread ----
__global__ __launch_bounds__(256) void convk(const float* __restrict__ in,
                                             short* __restrict__ out) {
    int i = blockIdx.x * 256 + threadIdx.x;
    float4 v = ((const float4*)in)[i];
    short4 s;
    s.x = f2b(v.x); s.y = f2b(v.y); s.z = f2b(v.z); s.w = f2b(v.w);
    ((short4*)out)[i] = s;
}

__device__ __forceinline__ void stv(float* p, float v) { *p = v; }
__device__ __forceinline__ void stv(short* p, float v) { *p = f2b(v); }

template <typename OT>
__global__ __launch_bounds__(256) void ln_kernel(const float* __restrict__ x,
                                                 const float* __restrict__ g,
                                                 const float* __restrict__ b,
                                                 OT* __restrict__ y) {
    int row = blockIdx.x;
    const float* xr = x + (long)row * Dh;
    OT* yr = y + (long)row * Dh;
    int tid = threadIdx.x;
    float v0 = xr[tid], v1 = xr[tid + 256];
    __shared__ float red[256];
    red[tid] = v0 + v1;
    __syncthreads();
    for (int o = 128; o > 0; o >>= 1) { if (tid < o) red[tid] += red[tid + o]; __syncthreads(); }
    float mean = red[0] * (1.0f / Dh);
    __syncthreads();
    float d0 = v0 - mean, d1 = v1 - mean;
    red[tid] = d0 * d0 + d1 * d1;
    __syncthreads();
    for (int o = 128; o > 0; o >>= 1) { if (tid < o) red[tid] += red[tid + o]; __syncthreads(); }
    float rstd = rsqrtf(red[0] * (1.0f / Dh) + 1e-5f);
    stv(&yr[tid], d0 * rstd * g[tid] + b[tid]);
    stv(&yr[tid + 256], d1 * rstd * g[tid + 256] + b[tid + 256]);
}

// ---- row softmax, f32 in, bf16 out (out of place) ----
__global__ __launch_bounds__(256) void softmax_bf16(const float* __restrict__ scb,
                                                    short* __restrict__ pbf) {
    const float* p = scb + (long)blockIdx.y * Nseq * Nseq + (long)blockIdx.x * Nseq;
    short* po = pbf + (long)blockIdx.y * Nseq * Nseq + (long)blockIdx.x * Nseq;
    int tid = threadIdx.x;
    float v[4];
    float mx = -INFINITY;
#pragma unroll
    for (int r = 0; r < 4; r++) { v[r] = p[tid + r * 256]; mx = fmaxf(mx, v[r]); }
    __shared__ float red[256];
    red[tid] = mx;
    __syncthreads();
    for (int o = 128; o > 0; o >>= 1) { if (tid < o) red[tid] = fmaxf(red[tid], red[tid + o]); __syncthreads(); }
    mx = red[0];
    __syncthreads();
    float s = 0.f;
#pragma unroll
    for (int r = 0; r < 4; r++) { v[r] = __expf(v[r] - mx); s += v[r]; }
    red[tid] = s;
    __syncthreads();
    for (int o = 128; o > 0; o >>= 1) { if (tid < o) red[tid] += red[tid + o]; __syncthreads(); }
    float inv = 1.0f / red[0];
#pragma unroll
    for (int r = 0; r < 4; r++) po[tid + r * 256] = f2b(v[r] * inv);
}

// ---- Vattn_t[slice][d][m] gather (bf16) ----
__global__ __launch_bounds__(256) void vattn_t(const short* __restrict__ Hv,
                                               const short* __restrict__ Vv,
                                               short* __restrict__ VaT) {
    int idx = blockIdx.x * 256 + threadIdx.x;
    int m = idx & 1023, d = (idx >> 10) & 127;
    int s = idx >> 17; int b = s >> 4, h = s & 15;
    short val;
    if (d < 32) val = Hv[((long)b * Nseq + m) * 512 + h * 32 + d];
    else {
        int c3 = (d - 32) >> 5, dd = (d - 32) & 31;
        val = Vv[(((long)b * Nseq + m) * 3 + c3) * 512 + h * 32 + dd];
    }
    VaT[idx] = val;
}

// ---- scaler = [Hn2 | ||V1||] as bf16 ----
__global__ __launch_bounds__(256) void scaler_k(const float* __restrict__ Hn2,
                                                const float* __restrict__ Vp,
                                                short* __restrict__ scaler) {
    int idx = blockIdx.x * 256 + threadIdx.x; // B*N*512
    int j = idx & 511;
    int row = idx >> 9;
    scaler[(long)row * 1024 + j] = f2b(Hn2[idx]);
    float ss = 0.f;
#pragma unroll
    for (int c = 0; c < 3; c++) {
        float v = Vp[((long)row * 3 + c) * 1024 + j];
        ss += v * v;
    }
    scaler[(long)row * 1024 + 512 + j] = f2b(sqrtf(ss));
}

// ---- final: H += s[:512]; V += s[512:] * V2 ----
__global__ __launch_bounds__(256) void final_k(float* __restrict__ outH,
                                               float* __restrict__ outV,
                                               const float* __restrict__ s,
                                               const float* __restrict__ Vp) {
    int idx = blockIdx.x * 256 + threadIdx.x; // B*N*512
    int j = idx & 511;
    int row = idx >> 9;
    outH[idx] += s[(long)row * 1024 + j];
    float vu = s[(long)row * 1024 + 512 + j];
#pragma unroll
    for (int c = 0; c < 3; c++) {
        long vi = ((long)row * 3 + c) * Dh + j;
        outV[vi] += vu * Vp[((long)row * 3 + c) * 1024 + 512 + j];
    }
}

extern "C" void kernel_launch(void* const* d_in, const int* in_sizes, int n_in,
                              void* d_out, int out_size, void* d_ws, size_t ws_size,
                              hipStream_t stream) {
    const float* H    = (const float*)d_in[0];
    const float* V    = (const float*)d_in[1];
    const float* Dm   = (const float*)d_in[2];
    const float* rbf  = (const float*)d_in[3];
    const int*   mask = (const int*)d_in[4];
    const float* Wq   = (const float*)d_in[5];
    const float* bq   = (const float*)d_in[6];
    const float* Wk   = (const float*)d_in[7];
    const float* bk   = (const float*)d_in[8];
    const float* Wvs  = (const float*)d_in[9];
    const float* bvs  = (const float*)d_in[10];
    const float* Wvv  = (const float*)d_in[11];
    const float* Wo   = (const float*)d_in[12];
    const float* bo   = (const float*)d_in[13];
    const float* Wvo  = (const float*)d_in[14];
    const float* ln1g = (const float*)d_in[15];
    const float* ln1b = (const float*)d_in[16];
    const float* Wlv  = (const float*)d_in[17];
    const float* W1   = (const float*)d_in[18];
    const float* b1   = (const float*)d_in[19];
    const float* W2   = (const float*)d_in[20];
    const float* b2   = (const float*)d_in[21];
    const float* ln2g = (const float*)d_in[22];
    const float* ln2b = (const float*)d_in[23];

    char* wsb = (char*)d_ws;
    auto KB = [&](long kb) { return (void*)(wsb + kb * 1024l); };
    // weights (persistent through the call)
    short* WqT  = (short*)KB(0);
    short* WkT  = (short*)KB(2048);
    short* WvsT = (short*)KB(4096);
    short* WvvT = (short*)KB(4608);
    short* WoT  = (short*)KB(5120);
    short* WvoT = (short*)KB(5632);
    short* WlvT = (short*)KB(6144);
    short* W1T  = (short*)KB(7168);
    short* W2T  = (short*)KB(11264);
    // phase 1
    short* HqB = (short*)KB(15360);
    short* HkB = (short*)KB(23552);
    short* HvB = (short*)KB(31744);
    short* VvR = (short*)KB(33792);
    short* VaT = (short*)KB(39936);
    short* Hn  = (short*)KB(48128);   // dead after projections
    short* Vbf = (short*)KB(50176);   // dead after VvR gemm
    float* scb = (float*)KB(48128);   // 4 slices f32, 16MB (overwrites Hn/Vbf later)
    short* Pbf = (short*)KB(64512);   // 4 slices bf16, 8MB
    short* Hres = (short*)KB(72704);
    short* Vres = (short*)KB(74752);  // ..80896
    // phase 2 (reuses dead phase-1 space; disjoint from Hres/Vres)
    float* Hn2    = (float*)KB(15360);
    short* Vbf2   = (short*)KB(19456);
    float* Vp     = (float*)KB(25600);
    short* scaler = (short*)KB(50176);
    short* t1     = (short*)KB(54272);
    float* sbuf   = (float*)KB(62464);

    float* outH = (float*)d_out;
    float* outV = outH + (size_t)Bc * Nseq * Dh;

    // weight transposes + converts
    tconv<<<dim3(64, 16), 256, 0, stream>>>(Wq, WqT, 512, 2048);
    tconv<<<dim3(64, 16), 256, 0, stream>>>(Wk, WkT, 512, 2048);
    tconv<<<dim3(16, 16), 256, 0, stream>>>(Wvs, WvsT, 512, 512);
    tconv<<<dim3(16, 16), 256, 0, stream>>>(Wvv, WvvT, 512, 512);
    tconv<<<dim3(16, 16), 256, 0, stream>>>(Wo, WoT, 512, 512);
    tconv<<<dim3(16, 16), 256, 0, stream>>>(Wvo, WvoT, 512, 512);
    tconv<<<dim3(32, 16), 256, 0, stream>>>(Wlv, WlvT, 512, 1024);
    tconv<<<dim3(64, 32), 256, 0, stream>>>(W1, W1T, 1024, 2048);
    tconv<<<dim3(32, 64), 256, 0, stream>>>(W2, W2T, 2048, 1024);
    convk<<<3072, 256, 0, stream>>>(V, Vbf);

    // LN1 -> bf16
    ln_kernel<short><<<2048, 256, 0, stream>>>(H, ln1g, ln1b, Hn);
    // projections (bf16 out)
    gemm_bf16<<<dim3(16, 16, 1), 256, 0, stream>>>(Hn, 512, 0, WqT, 512, 0, HqB, 2048, 0,
                                                   bq, nullptr, 0, 0, 512, 2);
    gemm_bf16<<<dim3(16, 16, 1), 256, 0, stream>>>(Hn, 512, 0, WkT, 512, 0, HkB, 2048, 0,
                                                   bk, nullptr, 0, 0, 512, 2);
    gemm_bf16<<<dim3(4, 16, 1), 256, 0, stream>>>(Hn, 512, 0, WvsT, 512, 0, HvB, 512, 0,
                                                  bvs, nullptr, 0, 0, 512, 2);
    gemm_bf16<<<dim3(4, 48, 1), 256, 0, stream>>>(Vbf, 512, 0, WvvT, 512, 0, VvR, 512, 0,
                                                  nullptr, nullptr, 0, 0, 512, 2);
    vattn_t<<<16384, 256, 0, stream>>>(HvB, VvR, VaT);

    // attention: 8 rounds x 4 slices
    for (int r = 0; r < 8; r++) {
        int slice0 = r * 4;
        score_mfma<<<dim3(8, 8, 4), 256, 0, stream>>>(HqB, HkB, rbf, Dm, mask, scb, slice0);
        softmax_bf16<<<dim3(1024, 4), 256, 0, stream>>>(scb, Pbf);
        pv_mfma<<<dim3(1, 8, 4), 256, 0, stream>>>(Pbf, VaT, Hres, Vres, slice0);
    }

    // output projections with residuals (f32 into d_out)
    gemm_bf16<<<dim3(4, 16, 1), 256, 0, stream>>>(Hres, 512, 0, WoT, 512, 0, outH, 512, 0,
                                                  bo, H, 512, 0, 512, 0);
    gemm_bf16<<<dim3(4, 48, 1), 256, 0, stream>>>(Vres, 512, 0, WvoT, 512, 0, outV, 512, 0,
                                                  nullptr, V, 512, 0, 512, 0);
    convk<<<3072, 256, 0, stream>>>(outV, Vbf2);
    ln_kernel<float><<<2048, 256, 0, stream>>>(outH, ln2g, ln2b, Hn2);
    // Vp = V_new @ Wlv (f32, needed for norm + final)
    gemm_bf16<<<dim3(8, 48, 1), 256, 0, stream>>>(Vbf2, 512, 0, WlvT, 512, 0, Vp, 1024, 0,
                                                  nullptr, nullptr, 0, 0, 512, 0);
    scaler_k<<<4096, 256, 0, stream>>>(Hn2, Vp, scaler);
    // FFN
    gemm_bf16<<<dim3(16, 16, 1), 256, 0, stream>>>(scaler, 1024, 0, W1T, 1024, 0, t1, 2048, 0,
                                                   b1, nullptr, 0, 0, 1024, 3);
    gemm_bf16<<<dim3(8, 16, 1), 256, 0, stream>>>(t1, 2048, 0, W2T, 2048, 0, sbuf, 1024, 0,
                                                  b2, nullptr, 0, 0, 2048, 0);
    final_k<<<4096, 256, 0, stream>>>(outH, outV, sbuf, Vp);
}

// Round 4
// 527.365 us; speedup vs baseline: 3.7345x; 1.4970x over previous
//
#include <hip/hip_runtime.h>
#include <math.h>

constexpr int Bc = 2, Nseq = 1024, Dh = 512, Nh = 16, Dhead = 32;
constexpr float FACT = 0.08838834764831845f; // 0.5/sqrt(32)

typedef __attribute__((ext_vector_type(8))) __bf16 bf16x8;
typedef __attribute__((ext_vector_type(4))) float f32x4;

__device__ __forceinline__ short f2b(float x) {
    union { float f; unsigned u; } v; v.f = x;
    unsigned r = v.u + 0x7fffu + ((v.u >> 16) & 1u);
    return (short)(r >> 16);
}

// ---- shared 128x128-tile bf16 MFMA mainloop (A[M][K], B[N][K], both row-major bf16) ----
// Register-staged LDS (global load -> ds_write_b128), XOR chunk swizzle.
__device__ __forceinline__ void mfma_loop(const short* __restrict__ A, int lda,
                                          const short* __restrict__ B, int ldb,
                                          int K, short* __restrict__ smA,
                                          short* __restrict__ smB, f32x4 acc[4][4]) {
    const int tid = threadIdx.x;
    const int lane = tid & 63;
    const int w = tid >> 6;
    const int wr = (w >> 1) * 64, wc = (w & 1) * 64;
    const int lr = lane & 15;
    const int srow = tid >> 3;  // 0..31
    const int scol = tid & 7;   // 16B chunk 0..7
    for (int k0 = 0; k0 < K; k0 += 64) {
        bf16x8 ta[4], tb[4];
#pragma unroll
        for (int r = 0; r < 4; r++) {
            int row = r * 32 + srow;
            ta[r] = *(const bf16x8*)(A + (long)row * lda + k0 + scol * 8);
            tb[r] = *(const bf16x8*)(B + (long)row * ldb + k0 + scol * 8);
        }
        __syncthreads();
#pragma unroll
        for (int r = 0; r < 4; r++) {
            int row = r * 32 + srow;
            int c = scol ^ (row & 7);
            *(bf16x8*)(smA + row * 64 + c * 8) = ta[r];
            *(bf16x8*)(smB + row * 64 + c * 8) = tb[r];
        }
        __syncthreads();
#pragma unroll
        for (int h = 0; h < 2; h++) {
            int cb = h * 4 + (lane >> 4);
            bf16x8 af[4], bv[4];
#pragma unroll
            for (int i = 0; i < 4; i++) {
                int row = wr + i * 16 + lr;
                af[i] = *(const bf16x8*)(smA + row * 64 + ((cb ^ (row & 7)) << 3));
            }
#pragma unroll
            for (int j = 0; j < 4; j++) {
                int row = wc + j * 16 + lr;
                bv[j] = *(const bf16x8*)(smB + row * 64 + ((cb ^ (row & 7)) << 3));
            }
#pragma unroll
            for (int i = 0; i < 4; i++)
#pragma unroll
                for (int j = 0; j < 4; j++)
                    acc[i][j] = __builtin_amdgcn_mfma_f32_16x16x32_bf16(af[i], bv[j], acc[i][j], 0, 0, 0);
        }
    }
}

// ---- generic GEMM: C = A @ B^T (+bias)(+resid)(silu), out f32 or bf16 ----
// flags: 1 = silu, 2 = output bf16
__global__ __launch_bounds__(256) void gemm_bf16(
    const short* __restrict__ A, int lda, long sAz,
    const short* __restrict__ B, int ldb, long sBz,
    void* __restrict__ C, int ldc, long sCz,
    const float* __restrict__ bias,
    const float* __restrict__ resid, int ldr, long sRz,
    int K, int flags)
{
    __shared__ short smA[128 * 64], smB[128 * 64];
    const long z = blockIdx.z;
    const short* Ab = A + z * sAz + (long)blockIdx.y * 128 * lda;
    const short* Bb = B + z * sBz + (long)blockIdx.x * 128 * ldb;
    f32x4 acc[4][4] = {};
    mfma_loop(Ab, lda, Bb, ldb, K, smA, smB, acc);
    const int tid = threadIdx.x, lane = tid & 63, w = tid >> 6;
    const int wr = (w >> 1) * 64, wc = (w & 1) * 64, lr = lane & 15, r0 = (lane >> 4) * 4;
    const int m0 = blockIdx.y * 128, n0 = blockIdx.x * 128;
    float* Cf = (float*)C; short* Cs = (short*)C;
    const float* rz = resid ? resid + z * sRz : nullptr;
#pragma unroll
    for (int i = 0; i < 4; i++)
#pragma unroll
        for (int j = 0; j < 4; j++) {
            int col = n0 + wc + j * 16 + lr;
            float bv = bias ? bias[col] : 0.f;
#pragma unroll
            for (int q = 0; q < 4; q++) {
                int row = m0 + wr + i * 16 + r0 + q;
                float c = acc[i][j][q] + bv;
                if (rz) c += rz[(long)row * ldr + col];
                if (flags & 1) c = c / (1.f + __expf(-c));
                long off = z * sCz + (long)row * ldc + col;
                if (flags & 2) Cs[off] = f2b(c); else Cf[off] = c;
            }
        }
}

// ---- fused flash attention: QK^T + (rbf + D + mask) bias + online softmax + PV ----
// grid (8 q-tiles, 32 slices), 512 threads (8 warps x 16 q-rows).
// K/V/P tiles in LDS (XOR-swizzled, register-staged); Q fragments in registers.
__global__ __launch_bounds__(512) void flash_attn(
    const short* __restrict__ Hq, const short* __restrict__ Hk,
    const short* __restrict__ VaT, const float* __restrict__ rbf,
    const float* __restrict__ Dm, const int* __restrict__ mask,
    short* __restrict__ Hres, short* __restrict__ Vres)
{
    __shared__ short smK[128 * 128];  // [m_local][d]
    __shared__ short smV[128 * 128];  // [d][m_local]
    __shared__ short smP[128 * 128];  // [q_row][m_local]
    const int s = blockIdx.y, b = s >> 4, h = s & 15;
    const int q0 = blockIdx.x * 128;
    const int tid = threadIdx.x, lane = tid & 63, w = tid >> 6;
    const int lr = lane & 15, hi = lane >> 4, r0 = hi * 4;
    // staging assignment: chunk c (0..15) within row, rows row4 + {0,32,64,96}
    const int c = tid & 15, row4 = tid >> 4;

    // Q fragments: rows w*16+lr, k = kk*32 + hi*8 (+e)
    bf16x8 qf[4];
    {
        const short* qb = Hq + ((long)b * Nseq + q0 + w * 16 + lr) * 2048 + h * 128 + hi * 8;
#pragma unroll
        for (int kk = 0; kk < 4; kk++) qf[kk] = *(const bf16x8*)(qb + kk * 32);
    }

    f32x4 oac[8] = {};            // O[row=w*16+r0+q][d=j*16+lr]
    float ml[4], ll[4];
#pragma unroll
    for (int q = 0; q < 4; q++) { ml[q] = -INFINITY; ll[q] = 0.f; }

    const short* Kg = Hk + (long)b * Nseq * 2048 + h * 128;
    const short* Vg = VaT + (long)s * 128 * Nseq;
    const float* rbb = rbf + ((long)s * Nseq + q0 + w * 16) * Nseq;
    const float* Dbb = Dm + ((long)b * Nseq + q0 + w * 16) * Nseq;
    const int* mp = mask + b * Nseq;

    for (int kt = 0; kt < 8; kt++) {
        // stage K, V tiles to registers
        bf16x8 tk[4], tv[4];
#pragma unroll
        for (int r = 0; r < 4; r++) {
            int row = r * 32 + row4;
            tk[r] = *(const bf16x8*)(Kg + (long)(kt * 128 + row) * 2048 + c * 8);
            tv[r] = *(const bf16x8*)(Vg + (long)row * Nseq + kt * 128 + c * 8);
        }
        __syncthreads();  // prior iter's LDS reads done
#pragma unroll
        for (int r = 0; r < 4; r++) {
            int row = r * 32 + row4;
            int pc = c ^ (row & 7);
            *(bf16x8*)(smK + row * 128 + pc * 8) = tk[r];
            *(bf16x8*)(smV + row * 128 + pc * 8) = tv[r];
        }
        __syncthreads();  // K/V visible
        // S = Q @ K^T  (S rows = q, cols = m_local)
        f32x4 sac[8] = {};
#pragma unroll
        for (int kk = 0; kk < 4; kk++) {
            int cb = kk * 4 + hi;
            bf16x8 bv[8];
#pragma unroll
            for (int j = 0; j < 8; j++) {
                int row = j * 16 + lr;
                bv[j] = *(const bf16x8*)(smK + row * 128 + ((cb ^ (row & 7)) << 3));
            }
#pragma unroll
            for (int j = 0; j < 8; j++)
                sac[j] = __builtin_amdgcn_mfma_f32_16x16x32_bf16(qf[kk], bv[j], sac[j], 0, 0, 0);
        }
        // bias + mask + online softmax
        float tmax[4];
#pragma unroll
        for (int q = 0; q < 4; q++) tmax[q] = -INFINITY;
#pragma unroll
        for (int j = 0; j < 8; j++) {
            int col = j * 16 + lr;
            int gm = kt * 128 + col;
            bool live = (mp[gm] != 0);
#pragma unroll
            for (int q = 0; q < 4; q++) {
                float x = sac[j][q] * FACT + rbb[(long)(r0 + q) * Nseq + gm]
                        + Dbb[(long)(r0 + q) * Nseq + gm];
                x = live ? x : -1e30f;
                sac[j][q] = x;
                tmax[q] = fmaxf(tmax[q], x);
            }
        }
#pragma unroll
        for (int st = 1; st < 16; st <<= 1)
#pragma unroll
            for (int q = 0; q < 4; q++) tmax[q] = fmaxf(tmax[q], __shfl_xor(tmax[q], st));
        float scale[4], rsum[4];
#pragma unroll
        for (int q = 0; q < 4; q++) {
            float mn = fmaxf(ml[q], tmax[q]);
            scale[q] = __expf(ml[q] - mn);
            ml[q] = mn;
            rsum[q] = 0.f;
        }
#pragma unroll
        for (int j = 0; j < 8; j++)
#pragma unroll
            for (int q = 0; q < 4; q++) {
                float p = __expf(sac[j][q] - ml[q]);
                sac[j][q] = p;
                rsum[q] += p;
            }
#pragma unroll
        for (int st = 1; st < 16; st <<= 1)
#pragma unroll
            for (int q = 0; q < 4; q++) rsum[q] += __shfl_xor(rsum[q], st);
#pragma unroll
        for (int q = 0; q < 4; q++) ll[q] = ll[q] * scale[q] + rsum[q];
#pragma unroll
        for (int j = 0; j < 8; j++)
#pragma unroll
            for (int q = 0; q < 4; q++) oac[j][q] *= scale[q];
        // P -> LDS (bf16, swizzled)
#pragma unroll
        for (int j = 0; j < 8; j++) {
            int col = j * 16 + lr;
            int ch = col >> 3, in8 = col & 7;
#pragma unroll
            for (int q = 0; q < 4; q++) {
                int row = w * 16 + r0 + q;
                smP[row * 128 + ((ch ^ (row & 7)) << 3) + in8] = f2b(sac[j][q]);
            }
        }
        __syncthreads();  // P visible
        // O += P @ V  (A = P rows, B = smV rows = d)
#pragma unroll
        for (int kk = 0; kk < 4; kk++) {
            int cb = kk * 4 + hi;
            int prow = w * 16 + lr;
            bf16x8 paf = *(const bf16x8*)(smP + prow * 128 + ((cb ^ (prow & 7)) << 3));
            bf16x8 bv[8];
#pragma unroll
            for (int j = 0; j < 8; j++) {
                int row = j * 16 + lr;
                bv[j] = *(const bf16x8*)(smV + row * 128 + ((cb ^ (row & 7)) << 3));
            }
#pragma unroll
            for (int j = 0; j < 8; j++)
                oac[j] = __builtin_amdgcn_mfma_f32_16x16x32_bf16(paf, bv[j], oac[j], 0, 0, 0);
        }
    }
    // normalize + scatter to Hres/Vres
    float inv[4];
#pragma unroll
    for (int q = 0; q < 4; q++) inv[q] = 1.f / ll[q];
#pragma unroll
    for (int j = 0; j < 8; j++) {
        int d = j * 16 + lr;
#pragma unroll
        for (int q = 0; q < 4; q++) {
            int n = q0 + w * 16 + r0 + q;
            float o = oac[j][q] * inv[q];
            if (d < 32) Hres[((long)b * Nseq + n) * 512 + h * 32 + d] = f2b(o);
            else {
                int c3 = (d - 32) >> 5, dd = (d - 32) & 31;
                Vres[(((long)b * Nseq + n) * 3 + c3) * 512 + h * 32 + dd] = f2b(o);
            }
        }
    }
}

// ---- weight transpose + f32->bf16: Wt[n][k] = W[k][n] ----
__global__ __launch_bounds__(256) void tconv(const float* __restrict__ W,
                                             short* __restrict__ Wt, int K, int N) {
    __shared__ float t[32][33];
    int n0 = blockIdx.x * 32, k0 = blockIdx.y * 32;
    int tx = threadIdx.x & 31, ty = threadIdx.x >> 5;
#pragma unroll
    for (int r = 0; r < 4; r++) t[ty + r * 8][tx] = W[(long)(k0 + ty + r * 8) * N + n0 + tx];
    __syncthreads();
#pragma unroll
    for (int r = 0; r < 4; r++) Wt[(long)(n0 + ty + r * 8) * K + k0 + tx] = f2b(t[tx][ty + r * 8]);
}

// ---- f32 -> bf16 convert, 4/thread ----
__global__ __launch_bounds__(256) void convk(const float* __restrict__ in,
                                             short* __restrict__ out) {
    int i = blockIdx.x * 256 + threadIdx.x;
    float4 v = ((const float4*)in)[i];
    short4 s;
    s.x = f2b(v.x); s.y = f2b(v.y); s.z = f2b(v.z); s.w = f2b(v.w);
    ((short4*)out)[i] = s;
}

__device__ __forceinline__ void stv(float* p, float v) { *p = v; }
__device__ __forceinline__ void stv(short* p, float v) { *p = f2b(v); }

template <typename OT>
__global__ __launch_bounds__(256) void ln_kernel(const float* __restrict__ x,
                                                 const float* __restrict__ g,
                                                 const float* __restrict__ b,
                                                 OT* __restrict__ y) {
    int row = blockIdx.x;
    const float* xr = x + (long)row * Dh;
    OT* yr = y + (long)row * Dh;
    int tid = threadIdx.x;
    float v0 = xr[tid], v1 = xr[tid + 256];
    __shared__ float red[256];
    red[tid] = v0 + v1;
    __syncthreads();
    for (int o = 128; o > 0; o >>= 1) { if (tid < o) red[tid] += red[tid + o]; __syncthreads(); }
    float mean = red[0] * (1.0f / Dh);
    __syncthreads();
    float d0 = v0 - mean, d1 = v1 - mean;
    red[tid] = d0 * d0 + d1 * d1;
    __syncthreads();
    for (int o = 128; o > 0; o >>= 1) { if (tid < o) red[tid] += red[tid + o]; __syncthreads(); }
    float rstd = rsqrtf(red[0] * (1.0f / Dh) + 1e-5f);
    stv(&yr[tid], d0 * rstd * g[tid] + b[tid]);
    stv(&yr[tid + 256], d1 * rstd * g[tid + 256] + b[tid + 256]);
}

// ---- Vattn_t[slice][d][m] gather (bf16) ----
__global__ __launch_bounds__(256) void vattn_t(const short* __restrict__ Hv,
                                               const short* __restrict__ Vv,
                                               short* __restrict__ VaT) {
    int idx = blockIdx.x * 256 + threadIdx.x;
    int m = idx & 1023, d = (idx >> 10) & 127;
    int s = idx >> 17; int b = s >> 4, h = s & 15;
    short val;
    if (d < 32) val = Hv[((long)b * Nseq + m) * 512 + h * 32 + d];
    else {
        int c3 = (d - 32) >> 5, dd = (d - 32) & 31;
        val = Vv[(((long)b * Nseq + m) * 3 + c3) * 512 + h * 32 + dd];
    }
    VaT[idx] = val;
}

// ---- scaler = [Hn2 | ||V1||] as bf16 ----
__global__ __launch_bounds__(256) void scaler_k(const float* __restrict__ Hn2,
                                                const float* __restrict__ Vp,
                                                short* __restrict__ scaler) {
    int idx = blockIdx.x * 256 + threadIdx.x; // B*N*512
    int j = idx & 511;
    int row = idx >> 9;
    scaler[(long)row * 1024 + j] = f2b(Hn2[idx]);
    float ss = 0.f;
#pragma unroll
    for (int c = 0; c < 3; c++) {
        float v = Vp[((long)row * 3 + c) * 1024 + j];
        ss += v * v;
    }
    scaler[(long)row * 1024 + 512 + j] = f2b(sqrtf(ss));
}

// ---- final: H += s[:512]; V += s[512:] * V2 ----
__global__ __launch_bounds__(256) void final_k(float* __restrict__ outH,
                                               float* __restrict__ outV,
                                               const float* __restrict__ s,
                                               const float* __restrict__ Vp) {
    int idx = blockIdx.x * 256 + threadIdx.x; // B*N*512
    int j = idx & 511;
    int row = idx >> 9;
    outH[idx] += s[(long)row * 1024 + j];
    float vu = s[(long)row * 1024 + 512 + j];
#pragma unroll
    for (int c = 0; c < 3; c++) {
        long vi = ((long)row * 3 + c) * Dh + j;
        outV[vi] += vu * Vp[((long)row * 3 + c) * 1024 + 512 + j];
    }
}

extern "C" void kernel_launch(void* const* d_in, const int* in_sizes, int n_in,
                              void* d_out, int out_size, void* d_ws, size_t ws_size,
                              hipStream_t stream) {
    const float* H    = (const float*)d_in[0];
    const float* V    = (const float*)d_in[1];
    const float* Dm   = (const float*)d_in[2];
    const float* rbf  = (const float*)d_in[3];
    const int*   mask = (const int*)d_in[4];
    const float* Wq   = (const float*)d_in[5];
    const float* bq   = (const float*)d_in[6];
    const float* Wk   = (const float*)d_in[7];
    const float* bk   = (const float*)d_in[8];
    const float* Wvs  = (const float*)d_in[9];
    const float* bvs  = (const float*)d_in[10];
    const float* Wvv  = (const float*)d_in[11];
    const float* Wo   = (const float*)d_in[12];
    const float* bo   = (const float*)d_in[13];
    const float* Wvo  = (const float*)d_in[14];
    const float* ln1g = (const float*)d_in[15];
    const float* ln1b = (const float*)d_in[16];
    const float* Wlv  = (const float*)d_in[17];
    const float* W1   = (const float*)d_in[18];
    const float* b1   = (const float*)d_in[19];
    const float* W2   = (const float*)d_in[20];
    const float* b2   = (const float*)d_in[21];
    const float* ln2g = (const float*)d_in[22];
    const float* ln2b = (const float*)d_in[23];

    char* wsb = (char*)d_ws;
    auto KB = [&](long kb) { return (void*)(wsb + kb * 1024l); };
    // weights (persistent through the call)
    short* WqT  = (short*)KB(0);
    short* WkT  = (short*)KB(2048);
    short* WvsT = (short*)KB(4096);
    short* WvvT = (short*)KB(4608);
    short* WoT  = (short*)KB(5120);
    short* WvoT = (short*)KB(5632);
    short* WlvT = (short*)KB(6144);
    short* W1T  = (short*)KB(7168);
    short* W2T  = (short*)KB(11264);
    // phase 1
    short* HqB = (short*)KB(15360);
    short* HkB = (short*)KB(23552);
    short* HvB = (short*)KB(31744);
    short* VvR = (short*)KB(33792);
    short* VaT = (short*)KB(39936);
    short* Hn  = (short*)KB(48128);   // dead after projections
    short* Vbf = (short*)KB(50176);   // dead after VvR gemm
    short* Hres = (short*)KB(72704);
    short* Vres = (short*)KB(74752);  // ..80896
    // phase 2 (reuses dead phase-1 space; disjoint from Hres/Vres)
    float* Hn2    = (float*)KB(15360);
    short* Vbf2   = (short*)KB(19456);
    float* Vp     = (float*)KB(25600);
    short* scaler = (short*)KB(50176);
    short* t1     = (short*)KB(54272);
    float* sbuf   = (float*)KB(62464);

    float* outH = (float*)d_out;
    float* outV = outH + (size_t)Bc * Nseq * Dh;

    // weight transposes + converts
    tconv<<<dim3(64, 16), 256, 0, stream>>>(Wq, WqT, 512, 2048);
    tconv<<<dim3(64, 16), 256, 0, stream>>>(Wk, WkT, 512, 2048);
    tconv<<<dim3(16, 16), 256, 0, stream>>>(Wvs, WvsT, 512, 512);
    tconv<<<dim3(16, 16), 256, 0, stream>>>(Wvv, WvvT, 512, 512);
    tconv<<<dim3(16, 16), 256, 0, stream>>>(Wo, WoT, 512, 512);
    tconv<<<dim3(16, 16), 256, 0, stream>>>(Wvo, WvoT, 512, 512);
    tconv<<<dim3(32, 16), 256, 0, stream>>>(Wlv, WlvT, 512, 1024);
    tconv<<<dim3(64, 32), 256, 0, stream>>>(W1, W1T, 1024, 2048);
    tconv<<<dim3(32, 64), 256, 0, stream>>>(W2, W2T, 2048, 1024);
    convk<<<3072, 256, 0, stream>>>(V, Vbf);

    // LN1 -> bf16
    ln_kernel<short><<<2048, 256, 0, stream>>>(H, ln1g, ln1b, Hn);
    // projections (bf16 out)
    gemm_bf16<<<dim3(16, 16, 1), 256, 0, stream>>>(Hn, 512, 0, WqT, 512, 0, HqB, 2048, 0,
                                                   bq, nullptr, 0, 0, 512, 2);
    gemm_bf16<<<dim3(16, 16, 1), 256, 0, stream>>>(Hn, 512, 0, WkT, 512, 0, HkB, 2048, 0,
                                                   bk, nullptr, 0, 0, 512, 2);
    gemm_bf16<<<dim3(4, 16, 1), 256, 0, stream>>>(Hn, 512, 0, WvsT, 512, 0, HvB, 512, 0,
                                                  bvs, nullptr, 0, 0, 512, 2);
    gemm_bf16<<<dim3(4, 48, 1), 256, 0, stream>>>(Vbf, 512, 0, WvvT, 512, 0, VvR, 512, 0,
                                                  nullptr, nullptr, 0, 0, 512, 2);
    vattn_t<<<16384, 256, 0, stream>>>(HvB, VvR, VaT);

    // fused flash attention (all 32 slices, one dispatch)
    flash_attn<<<dim3(8, 32), 512, 0, stream>>>(HqB, HkB, VaT, rbf, Dm, mask, Hres, Vres);

    // output projections with residuals (f32 into d_out)
    gemm_bf16<<<dim3(4, 16, 1), 256, 0, stream>>>(Hres, 512, 0, WoT, 512, 0, outH, 512, 0,
                                                  bo, H, 512, 0, 512, 0);
    gemm_bf16<<<dim3(4, 48, 1), 256, 0, stream>>>(Vres, 512, 0, WvoT, 512, 0, outV, 512, 0,
                                                  nullptr, V, 512, 0, 512, 0);
    convk<<<3072, 256, 0, stream>>>(outV, Vbf2);
    ln_kernel<float><<<2048, 256, 0, stream>>>(outH, ln2g, ln2b, Hn2);
    // Vp = V_new @ Wlv (f32, needed for norm + final)
    gemm_bf16<<<dim3(8, 48, 1), 256, 0, stream>>>(Vbf2, 512, 0, WlvT, 512, 0, Vp, 1024, 0,
                                                  nullptr, nullptr, 0, 0, 512, 0);
    scaler_k<<<4096, 256, 0, stream>>>(Hn2, Vp, scaler);
    // FFN
    gemm_bf16<<<dim3(16, 16, 1), 256, 0, stream>>>(scaler, 1024, 0, W1T, 1024, 0, t1, 2048, 0,
                                                   b1, nullptr, 0, 0, 1024, 3);
    gemm_bf16<<<dim3(8, 16, 1), 256, 0, stream>>>(t1, 2048, 0, W2T, 2048, 0, sbuf, 1024, 0,
                                                  b2, nullptr, 0, 0, 2048, 0);
    final_k<<<4096, 256, 0, stream>>>(outH, outV, sbuf, Vp);
}

// Round 5
// 385.629 us; speedup vs baseline: 5.1071x; 1.3675x over previous
//
#include <hip/hip_runtime.h>
#include <math.h>

constexpr int Bc = 2, Nseq = 1024, Dh = 512, Nh = 16, Dhead = 32;
constexpr float FACT = 0.08838834764831845f; // 0.5/sqrt(32)

typedef __attribute__((ext_vector_type(8))) __bf16 bf16x8;
typedef __attribute__((ext_vector_type(4))) float f32x4;

__device__ __forceinline__ short f2b(float x) {
    union { float f; unsigned u; } v; v.f = x;
    unsigned r = v.u + 0x7fffu + ((v.u >> 16) & 1u);
    return (short)(r >> 16);
}
__device__ __forceinline__ float b2f(short s) {
    union { unsigned u; float f; } v; v.u = ((unsigned)(unsigned short)s) << 16;
    return v.f;
}

// ---- shared 128x128-tile bf16 MFMA mainloop (A[M][K], B[N][K], both row-major bf16) ----
// Register-staged LDS (global load -> ds_write_b128), XOR chunk swizzle.
__device__ __forceinline__ void mfma_loop(const short* __restrict__ A, int lda,
                                          const short* __restrict__ B, int ldb,
                                          int K, short* __restrict__ smA,
                                          short* __restrict__ smB, f32x4 acc[4][4]) {
    const int tid = threadIdx.x;
    const int lane = tid & 63;
    const int w = tid >> 6;
    const int wr = (w >> 1) * 64, wc = (w & 1) * 64;
    const int lr = lane & 15;
    const int srow = tid >> 3;  // 0..31
    const int scol = tid & 7;   // 16B chunk 0..7
    for (int k0 = 0; k0 < K; k0 += 64) {
        bf16x8 ta[4], tb[4];
#pragma unroll
        for (int r = 0; r < 4; r++) {
            int row = r * 32 + srow;
            ta[r] = *(const bf16x8*)(A + (long)row * lda + k0 + scol * 8);
            tb[r] = *(const bf16x8*)(B + (long)row * ldb + k0 + scol * 8);
        }
        __syncthreads();
#pragma unroll
        for (int r = 0; r < 4; r++) {
            int row = r * 32 + srow;
            int c = scol ^ (row & 7);
            *(bf16x8*)(smA + row * 64 + c * 8) = ta[r];
            *(bf16x8*)(smB + row * 64 + c * 8) = tb[r];
        }
        __syncthreads();
#pragma unroll
        for (int h = 0; h < 2; h++) {
            int cb = h * 4 + (lane >> 4);
            bf16x8 af[4], bv[4];
#pragma unroll
            for (int i = 0; i < 4; i++) {
                int row = wr + i * 16 + lr;
                af[i] = *(const bf16x8*)(smA + row * 64 + ((cb ^ (row & 7)) << 3));
            }
#pragma unroll
            for (int j = 0; j < 4; j++) {
                int row = wc + j * 16 + lr;
                bv[j] = *(const bf16x8*)(smB + row * 64 + ((cb ^ (row & 7)) << 3));
            }
#pragma unroll
            for (int i = 0; i < 4; i++)
#pragma unroll
                for (int j = 0; j < 4; j++)
                    acc[i][j] = __builtin_amdgcn_mfma_f32_16x16x32_bf16(af[i], bv[j], acc[i][j], 0, 0, 0);
        }
    }
}

// ---- generic GEMM: C = A @ B^T (+bias)(+resid)(silu)(*FACT), out f32 or bf16 ----
// flags: 1 = silu, 2 = output bf16, 4 = scale by FACT
__global__ __launch_bounds__(256) void gemm_bf16(
    const short* __restrict__ A, int lda, long sAz,
    const short* __restrict__ B, int ldb, long sBz,
    void* __restrict__ C, int ldc, long sCz,
    const float* __restrict__ bias,
    const float* __restrict__ resid, int ldr, long sRz,
    int K, int flags)
{
    __shared__ short smA[128 * 64], smB[128 * 64];
    const long z = blockIdx.z;
    const short* Ab = A + z * sAz + (long)blockIdx.y * 128 * lda;
    const short* Bb = B + z * sBz + (long)blockIdx.x * 128 * ldb;
    f32x4 acc[4][4] = {};
    mfma_loop(Ab, lda, Bb, ldb, K, smA, smB, acc);
    const int tid = threadIdx.x, lane = tid & 63, w = tid >> 6;
    const int wr = (w >> 1) * 64, wc = (w & 1) * 64, lr = lane & 15, r0 = (lane >> 4) * 4;
    const int m0 = blockIdx.y * 128, n0 = blockIdx.x * 128;
    float* Cf = (float*)C; short* Cs = (short*)C;
    const float* rz = resid ? resid + z * sRz : nullptr;
#pragma unroll
    for (int i = 0; i < 4; i++)
#pragma unroll
        for (int j = 0; j < 4; j++) {
            int col = n0 + wc + j * 16 + lr;
            float bv = bias ? bias[col] : 0.f;
#pragma unroll
            for (int q = 0; q < 4; q++) {
                int row = m0 + wr + i * 16 + r0 + q;
                float c = acc[i][j][q] + bv;
                if (rz) c += rz[(long)row * ldr + col];
                if (flags & 1) c = c / (1.f + __expf(-c));
                if (flags & 4) c *= FACT;
                long off = z * sCz + (long)row * ldc + col;
                if (flags & 2) Cs[off] = f2b(c); else Cf[off] = c;
            }
        }
}

// ---- fused flash attention with LDS-staged bias (rbf + D + maskadd) ----
// grid (8 q-tiles, 32 slices), 512 threads (8 warps x 16 q-rows).
// Q in registers (FACT pre-folded); K/V in LDS; bias tile staged bf16 into the
// smP buffer (dead before P is written), all global reads coalesced float4.
__global__ __launch_bounds__(512) void flash_attn(
    const short* __restrict__ Hq, const short* __restrict__ Hk,
    const short* __restrict__ VaT, const float* __restrict__ rbf,
    const float* __restrict__ Dm, const float* __restrict__ maskadd,
    short* __restrict__ Hres, short* __restrict__ Vres)
{
    __shared__ short smK[128 * 128];  // [m_local][d]
    __shared__ short smV[128 * 128];  // [d][m_local]
    __shared__ short smP[128 * 128];  // bias tile, then P tile
    const int s = blockIdx.y, b = s >> 4, h = s & 15;
    const int q0 = blockIdx.x * 128;
    const int tid = threadIdx.x, lane = tid & 63, w = tid >> 6;
    const int lr = lane & 15, hi = lane >> 4, r0 = hi * 4;
    const int c = tid & 15, row4 = tid >> 4;       // K/V staging
    const int btr = tid >> 5, bc4 = (tid & 31) * 4; // bias staging

    bf16x8 qf[4];
    {
        const short* qb = Hq + ((long)b * Nseq + q0 + w * 16 + lr) * 2048 + h * 128 + hi * 8;
#pragma unroll
        for (int kk = 0; kk < 4; kk++) qf[kk] = *(const bf16x8*)(qb + kk * 32);
    }

    f32x4 oac[8] = {};
    float ml[4], ll[4];
#pragma unroll
    for (int q = 0; q < 4; q++) { ml[q] = -INFINITY; ll[q] = 0.f; }

    const short* Kg = Hk + (long)b * Nseq * 2048 + h * 128;
    const short* Vg = VaT + (long)s * 128 * Nseq;
    const float* rbb = rbf + ((long)s * Nseq + q0) * Nseq;
    const float* Dbb = Dm + ((long)b * Nseq + q0) * Nseq;
    const float* mab = maskadd + b * Nseq;

    for (int kt = 0; kt < 8; kt++) {
        // stage K, V to regs
        bf16x8 tk[4], tv[4];
#pragma unroll
        for (int r = 0; r < 4; r++) {
            int row = r * 32 + row4;
            tk[r] = *(const bf16x8*)(Kg + (long)(kt * 128 + row) * 2048 + c * 8);
            tv[r] = *(const bf16x8*)(Vg + (long)row * Nseq + kt * 128 + c * 8);
        }
        // stage bias tile to regs (coalesced float4)
        float4 bb[8];
#pragma unroll
        for (int it = 0; it < 8; it++) {
            int row = it * 16 + btr;
            int m0 = kt * 128 + bc4;
            float4 rv = *(const float4*)(rbb + (long)row * Nseq + m0);
            float4 dv = *(const float4*)(Dbb + (long)row * Nseq + m0);
            float4 mv = *(const float4*)(mab + m0);
            bb[it].x = rv.x + dv.x + mv.x;
            bb[it].y = rv.y + dv.y + mv.y;
            bb[it].z = rv.z + dv.z + mv.z;
            bb[it].w = rv.w + dv.w + mv.w;
        }
        __syncthreads();  // (1) prior iter's LDS reads complete
#pragma unroll
        for (int r = 0; r < 4; r++) {
            int row = r * 32 + row4;
            int pc = c ^ (row & 7);
            *(bf16x8*)(smK + row * 128 + pc * 8) = tk[r];
            *(bf16x8*)(smV + row * 128 + pc * 8) = tv[r];
        }
#pragma unroll
        for (int it = 0; it < 8; it++) {
            int row = it * 16 + btr;
            int sw = bc4 ^ (((row >> 2) & 7) << 4);
            short4 s4;
            s4.x = f2b(bb[it].x); s4.y = f2b(bb[it].y);
            s4.z = f2b(bb[it].z); s4.w = f2b(bb[it].w);
            *(short4*)(smP + row * 128 + sw) = s4;
        }
        __syncthreads();  // (2) K/V/bias visible
        // S = Q @ K^T
        f32x4 sac[8] = {};
#pragma unroll
        for (int kk = 0; kk < 4; kk++) {
            int cb = kk * 4 + hi;
            bf16x8 bv[8];
#pragma unroll
            for (int j = 0; j < 8; j++) {
                int row = j * 16 + lr;
                bv[j] = *(const bf16x8*)(smK + row * 128 + ((cb ^ (row & 7)) << 3));
            }
#pragma unroll
            for (int j = 0; j < 8; j++)
                sac[j] = __builtin_amdgcn_mfma_f32_16x16x32_bf16(qf[kk], bv[j], sac[j], 0, 0, 0);
        }
        // bias add (from LDS) + online softmax
        float tmax[4];
#pragma unroll
        for (int q = 0; q < 4; q++) tmax[q] = -INFINITY;
#pragma unroll
        for (int j = 0; j < 8; j++) {
#pragma unroll
            for (int q = 0; q < 4; q++) {
                int row = w * 16 + r0 + q;
                float bias = b2f(smP[row * 128 + ((j ^ ((row >> 2) & 7)) << 4) + lr]);
                float x = sac[j][q] + bias;
                sac[j][q] = x;
                tmax[q] = fmaxf(tmax[q], x);
            }
        }
#pragma unroll
        for (int st = 1; st < 16; st <<= 1)
#pragma unroll
            for (int q = 0; q < 4; q++) tmax[q] = fmaxf(tmax[q], __shfl_xor(tmax[q], st));
        float scale[4], rsum[4];
#pragma unroll
        for (int q = 0; q < 4; q++) {
            float mn = fmaxf(ml[q], tmax[q]);
            scale[q] = __expf(ml[q] - mn);
            ml[q] = mn;
            rsum[q] = 0.f;
        }
#pragma unroll
        for (int j = 0; j < 8; j++)
#pragma unroll
            for (int q = 0; q < 4; q++) {
                float p = __expf(sac[j][q] - ml[q]);
                sac[j][q] = p;
                rsum[q] += p;
            }
#pragma unroll
        for (int st = 1; st < 16; st <<= 1)
#pragma unroll
            for (int q = 0; q < 4; q++) rsum[q] += __shfl_xor(rsum[q], st);
#pragma unroll
        for (int q = 0; q < 4; q++) ll[q] = ll[q] * scale[q] + rsum[q];
#pragma unroll
        for (int j = 0; j < 8; j++)
#pragma unroll
            for (int q = 0; q < 4; q++) oac[j][q] *= scale[q];
        __syncthreads();  // (3) all bias reads done before P overwrites smP
        // P -> LDS (bf16, swizzled)
#pragma unroll
        for (int j = 0; j < 8; j++) {
            int col = j * 16 + lr;
            int ch = col >> 3, in8 = col & 7;
#pragma unroll
            for (int q = 0; q < 4; q++) {
                int row = w * 16 + r0 + q;
                smP[row * 128 + ((ch ^ (row & 7)) << 3) + in8] = f2b(sac[j][q]);
            }
        }
        __syncthreads();  // (4) P visible
        // O += P @ V
#pragma unroll
        for (int kk = 0; kk < 4; kk++) {
            int cb = kk * 4 + hi;
            int prow = w * 16 + lr;
            bf16x8 paf = *(const bf16x8*)(smP + prow * 128 + ((cb ^ (prow & 7)) << 3));
            bf16x8 bv[8];
#pragma unroll
            for (int j = 0; j < 8; j++) {
                int row = j * 16 + lr;
                bv[j] = *(const bf16x8*)(smV + row * 128 + ((cb ^ (row & 7)) << 3));
            }
#pragma unroll
            for (int j = 0; j < 8; j++)
                oac[j] = __builtin_amdgcn_mfma_f32_16x16x32_bf16(paf, bv[j], oac[j], 0, 0, 0);
        }
    }
    // normalize + scatter to Hres/Vres
    float inv[4];
#pragma unroll
    for (int q = 0; q < 4; q++) inv[q] = 1.f / ll[q];
#pragma unroll
    for (int j = 0; j < 8; j++) {
        int d = j * 16 + lr;
#pragma unroll
        for (int q = 0; q < 4; q++) {
            int n = q0 + w * 16 + r0 + q;
            float o = oac[j][q] * inv[q];
            if (d < 32) Hres[((long)b * Nseq + n) * 512 + h * 32 + d] = f2b(o);
            else {
                int c3 = (d - 32) >> 5, dd = (d - 32) & 31;
                Vres[(((long)b * Nseq + n) * 3 + c3) * 512 + h * 32 + dd] = f2b(o);
            }
        }
    }
}

// ---- mask -> additive float (0 / -1e30) ----
__global__ __launch_bounds__(256) void maskprep(const int* __restrict__ mask,
                                                float* __restrict__ maskadd) {
    int i = blockIdx.x * 256 + threadIdx.x;
    maskadd[i] = mask[i] ? 0.f : -1e30f;
}

// ---- weight transpose + f32->bf16: Wt[n][k] = W[k][n] ----
__global__ __launch_bounds__(256) void tconv(const float* __restrict__ W,
                                             short* __restrict__ Wt, int K, int N) {
    __shared__ float t[32][33];
    int n0 = blockIdx.x * 32, k0 = blockIdx.y * 32;
    int tx = threadIdx.x & 31, ty = threadIdx.x >> 5;
#pragma unroll
    for (int r = 0; r < 4; r++) t[ty + r * 8][tx] = W[(long)(k0 + ty + r * 8) * N + n0 + tx];
    __syncthreads();
#pragma unroll
    for (int r = 0; r < 4; r++) Wt[(long)(n0 + ty + r * 8) * K + k0 + tx] = f2b(t[tx][ty + r * 8]);
}

// ---- f32 -> bf16 convert, 4/thread ----
__global__ __launch_bounds__(256) void convk(const float* __restrict__ in,
                                             short* __restrict__ out) {
    int i = blockIdx.x * 256 + threadIdx.x;
    float4 v = ((const float4*)in)[i];
    short4 s;
    s.x = f2b(v.x); s.y = f2b(v.y); s.z = f2b(v.z); s.w = f2b(v.w);
    ((short4*)out)[i] = s;
}

__device__ __forceinline__ void stv(float* p, float v) { *p = v; }
__device__ __forceinline__ void stv(short* p, float v) { *p = f2b(v); }

template <typename OT>
__global__ __launch_bounds__(256) void ln_kernel(const float* __restrict__ x,
                                                 const float* __restrict__ g,
                                                 const float* __restrict__ b,
                                                 OT* __restrict__ y) {
    int row = blockIdx.x;
    const float* xr = x + (long)row * Dh;
    OT* yr = y + (long)row * Dh;
    int tid = threadIdx.x;
    float v0 = xr[tid], v1 = xr[tid + 256];
    __shared__ float red[256];
    red[tid] = v0 + v1;
    __syncthreads();
    for (int o = 128; o > 0; o >>= 1) { if (tid < o) red[tid] += red[tid + o]; __syncthreads(); }
    float mean = red[0] * (1.0f / Dh);
    __syncthreads();
    float d0 = v0 - mean, d1 = v1 - mean;
    red[tid] = d0 * d0 + d1 * d1;
    __syncthreads();
    for (int o = 128; o > 0; o >>= 1) { if (tid < o) red[tid] += red[tid + o]; __syncthreads(); }
    float rstd = rsqrtf(red[0] * (1.0f / Dh) + 1e-5f);
    stv(&yr[tid], d0 * rstd * g[tid] + b[tid]);
    stv(&yr[tid + 256], d1 * rstd * g[tid + 256] + b[tid + 256]);
}

// ---- Vattn_t[slice][d][m] gather (bf16) ----
__global__ __launch_bounds__(256) void vattn_t(const short* __restrict__ Hv,
                                               const short* __restrict__ Vv,
                                               short* __restrict__ VaT) {
    int idx = blockIdx.x * 256 + threadIdx.x;
    int m = idx & 1023, d = (idx >> 10) & 127;
    int s = idx >> 17; int b = s >> 4, h = s & 15;
    short val;
    if (d < 32) val = Hv[((long)b * Nseq + m) * 512 + h * 32 + d];
    else {
        int c3 = (d - 32) >> 5, dd = (d - 32) & 31;
        val = Vv[(((long)b * Nseq + m) * 3 + c3) * 512 + h * 32 + dd];
    }
    VaT[idx] = val;
}

// ---- scaler = [Hn2 | ||V1||] as bf16 ----
__global__ __launch_bounds__(256) void scaler_k(const float* __restrict__ Hn2,
                                                const float* __restrict__ Vp,
                                                short* __restrict__ scaler) {
    int idx = blockIdx.x * 256 + threadIdx.x; // B*N*512
    int j = idx & 511;
    int row = idx >> 9;
    scaler[(long)row * 1024 + j] = f2b(Hn2[idx]);
    float ss = 0.f;
#pragma unroll
    for (int c = 0; c < 3; c++) {
        float v = Vp[((long)row * 3 + c) * 1024 + j];
        ss += v * v;
    }
    scaler[(long)row * 1024 + 512 + j] = f2b(sqrtf(ss));
}

// ---- final: H += s[:512]; V += s[512:] * V2 ----
__global__ __launch_bounds__(256) void final_k(float* __restrict__ outH,
                                               float* __restrict__ outV,
                                               const float* __restrict__ s,
                                               const float* __restrict__ Vp) {
    int idx = blockIdx.x * 256 + threadIdx.x; // B*N*512
    int j = idx & 511;
    int row = idx >> 9;
    outH[idx] += s[(long)row * 1024 + j];
    float vu = s[(long)row * 1024 + 512 + j];
#pragma unroll
    for (int c = 0; c < 3; c++) {
        long vi = ((long)row * 3 + c) * Dh + j;
        outV[vi] += vu * Vp[((long)row * 3 + c) * 1024 + 512 + j];
    }
}

extern "C" void kernel_launch(void* const* d_in, const int* in_sizes, int n_in,
                              void* d_out, int out_size, void* d_ws, size_t ws_size,
                              hipStream_t stream) {
    const float* H    = (const float*)d_in[0];
    const float* V    = (const float*)d_in[1];
    const float* Dm   = (const float*)d_in[2];
    const float* rbf  = (const float*)d_in[3];
    const int*   mask = (const int*)d_in[4];
    const float* Wq   = (const float*)d_in[5];
    const float* bq   = (const float*)d_in[6];
    const float* Wk   = (const float*)d_in[7];
    const float* bk   = (const float*)d_in[8];
    const float* Wvs  = (const float*)d_in[9];
    const float* bvs  = (const float*)d_in[10];
    const float* Wvv  = (const float*)d_in[11];
    const float* Wo   = (const float*)d_in[12];
    const float* bo   = (const float*)d_in[13];
    const float* Wvo  = (const float*)d_in[14];
    const float* ln1g = (const float*)d_in[15];
    const float* ln1b = (const float*)d_in[16];
    const float* Wlv  = (const float*)d_in[17];
    const float* W1   = (const float*)d_in[18];
    const float* b1   = (const float*)d_in[19];
    const float* W2   = (const float*)d_in[20];
    const float* b2   = (const float*)d_in[21];
    const float* ln2g = (const float*)d_in[22];
    const float* ln2b = (const float*)d_in[23];

    char* wsb = (char*)d_ws;
    auto KB = [&](long kb) { return (void*)(wsb + kb * 1024l); };
    // weights (persistent through the call)
    short* WqT  = (short*)KB(0);
    short* WkT  = (short*)KB(2048);
    short* WvsT = (short*)KB(4096);
    short* WvvT = (short*)KB(4608);
    short* WoT  = (short*)KB(5120);
    short* WvoT = (short*)KB(5632);
    short* WlvT = (short*)KB(6144);
    short* W1T  = (short*)KB(7168);
    short* W2T  = (short*)KB(11264);
    // phase 1
    short* HqB = (short*)KB(15360);
    short* HkB = (short*)KB(23552);
    short* HvB = (short*)KB(31744);
    short* VvR = (short*)KB(33792);
    short* VaT = (short*)KB(39936);
    short* Hn  = (short*)KB(48128);   // dead after projections
    short* Vbf = (short*)KB(50176);   // dead after VvR gemm
    short* Hres = (short*)KB(72704);
    short* Vres = (short*)KB(74752);  // ..80896
    float* maskadd = (float*)KB(81920); // 8 KB
    // phase 2 (reuses dead phase-1 space; disjoint from Hres/Vres)
    float* Hn2    = (float*)KB(15360);
    short* Vbf2   = (short*)KB(19456);
    float* Vp     = (float*)KB(25600);
    short* scaler = (short*)KB(50176);
    short* t1     = (short*)KB(54272);
    float* sbuf   = (float*)KB(62464);

    float* outH = (float*)d_out;
    float* outV = outH + (size_t)Bc * Nseq * Dh;

    // weight transposes + converts
    tconv<<<dim3(64, 16), 256, 0, stream>>>(Wq, WqT, 512, 2048);
    tconv<<<dim3(64, 16), 256, 0, stream>>>(Wk, WkT, 512, 2048);
    tconv<<<dim3(16, 16), 256, 0, stream>>>(Wvs, WvsT, 512, 512);
    tconv<<<dim3(16, 16), 256, 0, stream>>>(Wvv, WvvT, 512, 512);
    tconv<<<dim3(16, 16), 256, 0, stream>>>(Wo, WoT, 512, 512);
    tconv<<<dim3(16, 16), 256, 0, stream>>>(Wvo, WvoT, 512, 512);
    tconv<<<dim3(32, 16), 256, 0, stream>>>(Wlv, WlvT, 512, 1024);
    tconv<<<dim3(64, 32), 256, 0, stream>>>(W1, W1T, 1024, 2048);
    tconv<<<dim3(32, 64), 256, 0, stream>>>(W2, W2T, 2048, 1024);
    convk<<<3072, 256, 0, stream>>>(V, Vbf);
    maskprep<<<8, 256, 0, stream>>>(mask, maskadd);

    // LN1 -> bf16
    ln_kernel<short><<<2048, 256, 0, stream>>>(H, ln1g, ln1b, Hn);
    // projections (bf16 out; Hq pre-scaled by FACT)
    gemm_bf16<<<dim3(16, 16, 1), 256, 0, stream>>>(Hn, 512, 0, WqT, 512, 0, HqB, 2048, 0,
                                                   bq, nullptr, 0, 0, 512, 6);
    gemm_bf16<<<dim3(16, 16, 1), 256, 0, stream>>>(Hn, 512, 0, WkT, 512, 0, HkB, 2048, 0,
                                                   bk, nullptr, 0, 0, 512, 2);
    gemm_bf16<<<dim3(4, 16, 1), 256, 0, stream>>>(Hn, 512, 0, WvsT, 512, 0, HvB, 512, 0,
                                                  bvs, nullptr, 0, 0, 512, 2);
    gemm_bf16<<<dim3(4, 48, 1), 256, 0, stream>>>(Vbf, 512, 0, WvvT, 512, 0, VvR, 512, 0,
                                                  nullptr, nullptr, 0, 0, 512, 2);
    vattn_t<<<16384, 256, 0, stream>>>(HvB, VvR, VaT);

    // fused flash attention (all 32 slices, one dispatch)
    flash_attn<<<dim3(8, 32), 512, 0, stream>>>(HqB, HkB, VaT, rbf, Dm, maskadd, Hres, Vres);

    // output projections with residuals (f32 into d_out)
    gemm_bf16<<<dim3(4, 16, 1), 256, 0, stream>>>(Hres, 512, 0, WoT, 512, 0, outH, 512, 0,
                                                  bo, H, 512, 0, 512, 0);
    gemm_bf16<<<dim3(4, 48, 1), 256, 0, stream>>>(Vres, 512, 0, WvoT, 512, 0, outV, 512, 0,
                                                  nullptr, V, 512, 0, 512, 0);
    convk<<<3072, 256, 0, stream>>>(outV, Vbf2);
    ln_kernel<float><<<2048, 256, 0, stream>>>(outH, ln2g, ln2b, Hn2);
    // Vp = V_new @ Wlv (f32, needed for norm + final)
    gemm_bf16<<<dim3(8, 48, 1), 256, 0, stream>>>(Vbf2, 512, 0, WlvT, 512, 0, Vp, 1024, 0,
                                                  nullptr, nullptr, 0, 0, 512, 0);
    scaler_k<<<4096, 256, 0, stream>>>(Hn2, Vp, scaler);
    // FFN
    gemm_bf16<<<dim3(16, 16, 1), 256, 0, stream>>>(scaler, 1024, 0, W1T, 1024, 0, t1, 2048, 0,
                                                   b1, nullptr, 0, 0, 1024, 3);
    gemm_bf16<<<dim3(8, 16, 1), 256, 0, stream>>>(t1, 2048, 0, W2T, 2048, 0, sbuf, 1024, 0,
                                                  b2, nullptr, 0, 0, 2048, 0);
    final_k<<<4096, 256, 0, stream>>>(outH, outV, sbuf, Vp);
}